// Round 4
// baseline (668.004 us; speedup 1.0000x reference)
//
#include <hip/hip_runtime.h>
#include <stdint.h>

#define Bb 8
#define Tt 32
#define Ee 4096
#define NQ 32
#define NKV 8
#define HD 128
#define CACHE_S 8192
#define SSPLIT 8
#define SCALE_F 0.08838834764831845f  // 1/sqrt(128)

typedef _Float16 half8 __attribute__((ext_vector_type(8)));
typedef _Float16 half4 __attribute__((ext_vector_type(4)));
typedef float f32x4 __attribute__((ext_vector_type(4)));

static __device__ __forceinline__ _Float16 f2h(float f) { return (_Float16)f; }

// ---------------------------------------------------------------------------
// Split-K GEMM: Cpart[z] = A[M x Kc] * W[N x Kc]^T for K-chunk z. fp32 in/out,
// f16 MFMA. 64x64 tiles. Weight selected among {W0,W1,W2} by n0 (fused QKV).
// ---------------------------------------------------------------------------
__global__ __launch_bounds__(256) void gemm_nt_sk(
    const float* __restrict__ A, const float* __restrict__ W0,
    const float* __restrict__ W1, const float* __restrict__ W2,
    int nsplit1, int nsplit2, float* __restrict__ Cpart, size_t part_stride,
    int K, int Kc, int ldc) {
  __shared__ _Float16 As[64][72];
  __shared__ _Float16 Ws[64][72];
  const int n0 = blockIdx.x * 64;
  const int m0 = blockIdx.y * 64;
  const int kp = blockIdx.z;
  const int kbase = kp * Kc;
  const float* Wp;
  int nr0;
  if (n0 < nsplit1) { Wp = W0; nr0 = n0; }
  else if (n0 < nsplit2) { Wp = W1; nr0 = n0 - nsplit1; }
  else { Wp = W2; nr0 = n0 - nsplit2; }
  const int tid = threadIdx.x;
  const int lane = tid & 63;
  const int wave = tid >> 6;
  const int wm = (wave >> 1) * 32;
  const int wn = (wave & 1) * 32;
  const int l15 = lane & 15;
  const int quad = lane >> 4;
  const int sr = tid >> 4;        // staging row 0..15 (+p*16)
  const int sc = (tid & 15) * 4;  // staging col (floats)

  f32x4 acc[2][2];
#pragma unroll
  for (int i = 0; i < 2; i++)
#pragma unroll
    for (int j = 0; j < 2; j++) acc[i][j] = f32x4{0.f, 0.f, 0.f, 0.f};

  float4 pa[4], pw[4];
#pragma unroll
  for (int p = 0; p < 4; p++) {
    const int r = sr + p * 16;
    pa[p] = *(const float4*)&A[(size_t)(m0 + r) * K + kbase + sc];
    pw[p] = *(const float4*)&Wp[(size_t)(nr0 + r) * K + kbase + sc];
  }

  for (int k0 = 0; k0 < Kc; k0 += 64) {
    __syncthreads();
#pragma unroll
    for (int p = 0; p < 4; p++) {
      const int r = sr + p * 16;
      half4 ha = {f2h(pa[p].x), f2h(pa[p].y), f2h(pa[p].z), f2h(pa[p].w)};
      *(half4*)&As[r][sc] = ha;
      half4 hw = {f2h(pw[p].x), f2h(pw[p].y), f2h(pw[p].z), f2h(pw[p].w)};
      *(half4*)&Ws[r][sc] = hw;
    }
    __syncthreads();
    if (k0 + 64 < Kc) {  // prefetch next K-tile (overlaps MFMA below)
#pragma unroll
      for (int p = 0; p < 4; p++) {
        const int r = sr + p * 16;
        pa[p] = *(const float4*)&A[(size_t)(m0 + r) * K + kbase + k0 + 64 + sc];
        pw[p] = *(const float4*)&Wp[(size_t)(nr0 + r) * K + kbase + k0 + 64 + sc];
      }
    }
#pragma unroll
    for (int ks = 0; ks < 2; ks++) {
      const int kc = ks * 32 + quad * 8;
      half8 af[2], wf[2];
#pragma unroll
      for (int i = 0; i < 2; i++) {
        af[i] = *(const half8*)&As[wm + i * 16 + l15][kc];
        wf[i] = *(const half8*)&Ws[wn + i * 16 + l15][kc];
      }
#pragma unroll
      for (int i = 0; i < 2; i++)
#pragma unroll
        for (int j = 0; j < 2; j++)
          acc[i][j] = __builtin_amdgcn_mfma_f32_16x16x32_f16(af[i], wf[j],
                                                             acc[i][j], 0, 0, 0);
    }
  }
  float* Cp = Cpart + (size_t)kp * part_stride;
#pragma unroll
  for (int i = 0; i < 2; i++) {
    const int mr = m0 + wm + i * 16 + quad * 4;
#pragma unroll
    for (int j = 0; j < 2; j++) {
      const int nc = n0 + wn + j * 16 + l15;
#pragma unroll
      for (int r = 0; r < 4; r++)
        Cp[(size_t)(mr + r) * ldc + nc] = acc[i][j][r];
    }
  }
}

// ---------------------------------------------------------------------------
// Sum 4 split-K partials of qkv + RoPE (bugged: angle from HEAD index) +
// scatter to qw (B,NQ,T,HD), kw/vw (B,NKV,T,HD).
// ---------------------------------------------------------------------------
__global__ __launch_bounds__(256) void rope_scatter(
    const float* __restrict__ qkvp, float* __restrict__ qw,
    float* __restrict__ kw, float* __restrict__ vw) {
  const int pid = blockIdx.x * 256 + threadIdx.x;
  const int m = pid / 3072;
  const int c = pid - m * 3072;
  const int n = c * 2;
  const int b = m >> 5;
  const int t = m & 31;
  const size_t base = (size_t)m * 6144 + n;
  float a0 = 0.f, a1 = 0.f;
#pragma unroll
  for (int p = 0; p < 4; p++) {
    const float2 v = *(const float2*)&qkvp[p * 1572864 + base];
    a0 += v.x;
    a1 += v.y;
  }
  if (n < 4096) {  // q
    const int h = n >> 7;
    const int j = (n & 127) >> 1;
    const float invf = powf(10000.0f, -(float)j * (1.0f / 64.0f));
    float sn, cs;
    sincosf((float)h * invf, &sn, &cs);
    float* dst = qw + ((size_t)(b * NQ + h) * Tt + t) * HD + (j << 1);
    dst[0] = a0 * cs - a1 * sn;
    dst[1] = a0 * sn + a1 * cs;
  } else if (n < 5120) {  // k
    const int nn = n - 4096;
    const int h = nn >> 7;
    const int j = (nn & 127) >> 1;
    const float invf = powf(10000.0f, -(float)j * (1.0f / 64.0f));
    float sn, cs;
    sincosf((float)h * invf, &sn, &cs);
    float* dst = kw + ((size_t)(b * NKV + h) * Tt + t) * HD + (j << 1);
    dst[0] = a0 * cs - a1 * sn;
    dst[1] = a0 * sn + a1 * cs;
  } else {  // v
    const int nn = n - 5120;
    const int h = nn >> 7;
    const int d = nn & 127;
    float* dst = vw + ((size_t)(b * NKV + h) * Tt + t) * HD + d;
    dst[0] = a0;
    dst[1] = a1;
  }
}

// ---------------------------------------------------------------------------
// Flash-decode attention partials. Block = (b, kv-head g, split). 4 waves =
// 4 GQA q-heads. 32-key chunks staged in LDS; TWO-deep register prefetch
// (A/B sets, 2x-unrolled chunk loop) to cover ~900-cycle HBM latency.
// ---------------------------------------------------------------------------
__global__ __launch_bounds__(256) void attn_partial(
    const float* __restrict__ qw, const float* __restrict__ kw,
    const float* __restrict__ vw, const float* __restrict__ cacheK,
    const float* __restrict__ cacheV, const int* __restrict__ startp,
    float* __restrict__ pO, float* __restrict__ pM, float* __restrict__ pL) {
  const int blk = blockIdx.x;
  const int split = blk & (SSPLIT - 1);
  const int g = (blk / SSPLIT) & (NKV - 1);
  const int b = blk / (SSPLIT * NKV);
  const int start = *startp;
  const int end = start + Tt;
  int cl = ((end + SSPLIT * 32 - 1) / (SSPLIT * 32)) * 32;
  const int s_begin = split * cl;
  int s_end = s_begin + cl;
  if (s_end > end) s_end = end;

  const int tid = threadIdx.x;
  const int lane = tid & 63;
  const int wave = tid >> 6;
  const int l15 = lane & 15;
  const int quad = lane >> 4;
  const int h = g * 4 + wave;

  __shared__ _Float16 Ks[32][136];
  __shared__ _Float16 Vt[128][40];   // transposed V: d x keys
  __shared__ _Float16 Ps[4][32][40];

  const int str = tid >> 3;        // key row 0..31
  const int stc = (tid & 7) * 4;   // col base (floats), +u*32

  float4 pkA[4], pvA[4], pkB[4], pvB[4];
  auto load_chunk = [&](int s0, float4* pk, float4* pv) {
    const int sg = s0 + str;
    const bool valid = sg < end;
    const float* krow;
    const float* vrow;
    if (sg < start) {
      const size_t off = (((size_t)b * CACHE_S + sg) * NKV + g) * HD;
      krow = cacheK + off;
      vrow = cacheV + off;
    } else {
      int loc = sg - start;
      if (loc > Tt - 1) loc = Tt - 1;
      const size_t off = ((size_t)(b * NKV + g) * Tt + loc) * HD;
      krow = kw + off;
      vrow = vw + off;
    }
#pragma unroll
    for (int u = 0; u < 4; u++) {
      const int cc = stc + u * 32;
      pk[u] = valid ? *(const float4*)&krow[cc] : make_float4(0.f, 0.f, 0.f, 0.f);
      pv[u] = valid ? *(const float4*)&vrow[cc] : make_float4(0.f, 0.f, 0.f, 0.f);
    }
  };
  auto commit_chunk = [&](const float4* pk, const float4* pv) {
#pragma unroll
    for (int u = 0; u < 4; u++) {
      const int cc = stc + u * 32;
      half4 hk = {f2h(pk[u].x), f2h(pk[u].y), f2h(pk[u].z), f2h(pk[u].w)};
      *(half4*)&Ks[str][cc] = hk;
      Vt[cc + 0][str] = f2h(pv[u].x);
      Vt[cc + 1][str] = f2h(pv[u].y);
      Vt[cc + 2][str] = f2h(pv[u].z);
      Vt[cc + 3][str] = f2h(pv[u].w);
    }
  };

  // issue chunk loads first (longest latency stream)
  load_chunk(s_begin, pkA, pvA);
  if (s_begin + 32 < s_end) load_chunk(s_begin + 32, pkB, pvB);

  // Q fragments (A-operand)
  half8 qf[2][4];
#pragma unroll
  for (int mt = 0; mt < 2; mt++) {
    const int t = mt * 16 + l15;
    const float* qrow = qw + ((size_t)(b * NQ + h) * Tt + t) * HD;
#pragma unroll
    for (int ks = 0; ks < 4; ks++) {
      const int d0 = ks * 32 + quad * 8;
      float4 v0 = *(const float4*)&qrow[d0];
      float4 v1 = *(const float4*)&qrow[d0 + 4];
      half8 hq = {f2h(v0.x), f2h(v0.y), f2h(v0.z), f2h(v0.w),
                  f2h(v1.x), f2h(v1.y), f2h(v1.z), f2h(v1.w)};
      qf[mt][ks] = hq;
    }
  }

  f32x4 Oacc[2][8];
#pragma unroll
  for (int mt = 0; mt < 2; mt++)
#pragma unroll
    for (int dt = 0; dt < 8; dt++) Oacc[mt][dt] = f32x4{0.f, 0.f, 0.f, 0.f};
  float mrow[2][4], lrow[2][4];
#pragma unroll
  for (int mt = 0; mt < 2; mt++)
#pragma unroll
    for (int rr = 0; rr < 4; rr++) { mrow[mt][rr] = -1e30f; lrow[mt][rr] = 0.f; }

  auto compute_chunk = [&](int s0) {
    // ---- scores ----
    f32x4 st[2][2];
#pragma unroll
    for (int mt = 0; mt < 2; mt++)
#pragma unroll
      for (int nt = 0; nt < 2; nt++) st[mt][nt] = f32x4{0.f, 0.f, 0.f, 0.f};
#pragma unroll
    for (int nt = 0; nt < 2; nt++) {
#pragma unroll
      for (int ks = 0; ks < 4; ks++) {
        half8 kf = *(const half8*)&Ks[nt * 16 + l15][ks * 32 + quad * 8];
        st[0][nt] = __builtin_amdgcn_mfma_f32_16x16x32_f16(qf[0][ks], kf, st[0][nt], 0, 0, 0);
        st[1][nt] = __builtin_amdgcn_mfma_f32_16x16x32_f16(qf[1][ks], kf, st[1][nt], 0, 0, 0);
      }
    }
#pragma unroll
    for (int mt = 0; mt < 2; mt++)
#pragma unroll
      for (int nt = 0; nt < 2; nt++)
#pragma unroll
        for (int rr = 0; rr < 4; rr++) {
          const int t = mt * 16 + quad * 4 + rr;
          const int sg = s0 + nt * 16 + l15;
          const float sv = st[mt][nt][rr] * SCALE_F;
          const bool masked = (sg > start + t) || (sg >= end);
          st[mt][nt][rr] = masked ? -1e30f : sv;
        }
    // ---- online softmax ----
#pragma unroll
    for (int mt = 0; mt < 2; mt++) {
      float rmax[4], rsum[4], al[4];
#pragma unroll
      for (int rr = 0; rr < 4; rr++)
        rmax[rr] = fmaxf(st[mt][0][rr], st[mt][1][rr]);
      for (int mm = 1; mm < 16; mm <<= 1)
#pragma unroll
        for (int rr = 0; rr < 4; rr++)
          rmax[rr] = fmaxf(rmax[rr], __shfl_xor(rmax[rr], mm));
#pragma unroll
      for (int rr = 0; rr < 4; rr++) {
        const float mn = fmaxf(mrow[mt][rr], rmax[rr]);
        al[rr] = __expf(mrow[mt][rr] - mn);
        mrow[mt][rr] = mn;
      }
#pragma unroll
      for (int nt = 0; nt < 2; nt++)
#pragma unroll
        for (int rr = 0; rr < 4; rr++)
          st[mt][nt][rr] = __expf(st[mt][nt][rr] - mrow[mt][rr]);
#pragma unroll
      for (int rr = 0; rr < 4; rr++) rsum[rr] = st[mt][0][rr] + st[mt][1][rr];
      for (int mm = 1; mm < 16; mm <<= 1)
#pragma unroll
        for (int rr = 0; rr < 4; rr++) rsum[rr] += __shfl_xor(rsum[rr], mm);
#pragma unroll
      for (int rr = 0; rr < 4; rr++)
        lrow[mt][rr] = lrow[mt][rr] * al[rr] + rsum[rr];
#pragma unroll
      for (int nt = 0; nt < 2; nt++)
#pragma unroll
        for (int rr = 0; rr < 4; rr++)
          Ps[wave][mt * 16 + quad * 4 + rr][nt * 16 + l15] = f2h(st[mt][nt][rr]);
#pragma unroll
      for (int dt = 0; dt < 8; dt++)
#pragma unroll
        for (int rr = 0; rr < 4; rr++) Oacc[mt][dt][rr] *= al[rr];
    }
    // ---- PV ----
    half8 pf0 = *(const half8*)&Ps[wave][l15][quad * 8];
    half8 pf1 = *(const half8*)&Ps[wave][16 + l15][quad * 8];
#pragma unroll
    for (int dt = 0; dt < 8; dt++) {
      half8 vf = *(const half8*)&Vt[dt * 16 + l15][quad * 8];
      Oacc[0][dt] = __builtin_amdgcn_mfma_f32_16x16x32_f16(pf0, vf, Oacc[0][dt], 0, 0, 0);
      Oacc[1][dt] = __builtin_amdgcn_mfma_f32_16x16x32_f16(pf1, vf, Oacc[1][dt], 0, 0, 0);
    }
  };

  for (int s0 = s_begin; s0 < s_end; s0 += 64) {
    // chunk s0 (buffer A)
    __syncthreads();
    commit_chunk(pkA, pvA);
    __syncthreads();
    if (s0 + 64 < s_end) load_chunk(s0 + 64, pkA, pvA);  // 2 chunks ahead
    compute_chunk(s0);
    // chunk s0+32 (buffer B)
    if (s0 + 32 < s_end) {
      __syncthreads();
      commit_chunk(pkB, pvB);
      __syncthreads();
      if (s0 + 96 < s_end) load_chunk(s0 + 96, pkB, pvB);
      compute_chunk(s0 + 32);
    }
  }

  const size_t rowbase = (size_t)(b * NQ + h) * Tt;
#pragma unroll
  for (int mt = 0; mt < 2; mt++)
#pragma unroll
    for (int rr = 0; rr < 4; rr++) {
      const int t = mt * 16 + quad * 4 + rr;
      const size_t pbase = ((rowbase + t) * SSPLIT + split) * (size_t)HD;
#pragma unroll
      for (int dt = 0; dt < 8; dt++)
        pO[pbase + dt * 16 + l15] = Oacc[mt][dt][rr];
      if (l15 == 0) {
        pM[(rowbase + t) * SSPLIT + split] = mrow[mt][rr];
        pL[(rowbase + t) * SSPLIT + split] = lrow[mt][rr];
      }
    }
}

// ---------------------------------------------------------------------------
__global__ __launch_bounds__(128) void attn_combine(
    const float* __restrict__ pO, const float* __restrict__ pM,
    const float* __restrict__ pL, float* __restrict__ att) {
  const int row = blockIdx.x;  // (b*NQ + h)*T + t
  const int d = threadIdx.x;
  float m[SSPLIT], l[SSPLIT];
  float ms = -3.0e30f;
#pragma unroll
  for (int i = 0; i < SSPLIT; i++) {
    m[i] = pM[row * SSPLIT + i];
    l[i] = pL[row * SSPLIT + i];
    ms = fmaxf(ms, m[i]);
  }
  float ls = 0.f, o = 0.f;
#pragma unroll
  for (int i = 0; i < SSPLIT; i++) {
    const float w = __expf(m[i] - ms);
    ls += l[i] * w;
    o += pO[((size_t)row * SSPLIT + i) * HD + d] * w;
  }
  o /= fmaxf(ls, 1e-30f);
  const int b = row / (NQ * Tt);
  const int hh = (row / Tt) % NQ;
  const int t = row % Tt;
  att[((size_t)(b * Tt + t)) * Ee + hh * HD + d] = o;
}

// ---------------------------------------------------------------------------
// out = p0+p1+p2+p3 (Wo split-K reduce), float4-vectorized.
// ---------------------------------------------------------------------------
__global__ __launch_bounds__(256) void reduce4(const float* __restrict__ p,
                                               float* __restrict__ out) {
  const int i = (blockIdx.x * 256 + threadIdx.x) * 4;
  float4 a = *(const float4*)&p[i];
  float4 b = *(const float4*)&p[i + 1048576];
  float4 c = *(const float4*)&p[i + 2097152];
  float4 d = *(const float4*)&p[i + 3145728];
  float4 r = make_float4(a.x + b.x + c.x + d.x, a.y + b.y + c.y + d.y,
                         a.z + b.z + c.z + d.z, a.w + b.w + c.w + d.w);
  *(float4*)&out[i] = r;
}

// ---------------------------------------------------------------------------
extern "C" void kernel_launch(void* const* d_in, const int* in_sizes, int n_in,
                              void* d_out, int out_size, void* d_ws,
                              size_t ws_size, hipStream_t stream) {
  const float* x = (const float*)d_in[0];
  const int* startp = (const int*)d_in[1];
  const float* cacheK = (const float*)d_in[2];
  const float* cacheV = (const float*)d_in[3];
  const float* Wq = (const float*)d_in[4];
  const float* Wk = (const float*)d_in[5];
  const float* Wv = (const float*)d_in[6];
  const float* Wo = (const float*)d_in[7];
  float* out = (float*)d_out;
  float* ws = (float*)d_ws;

  // workspace layout (floats)
  float* qkvp = ws;                     // 4 x 1,572,864 = 6,291,456
  float* pO = qkvp + 6291456;           // 8192*SSPLIT*128 = 8,388,608
  float* qw = pO + 8388608;             // 1,048,576
  float* kw = qw + 1048576;             // 262,144
  float* vw = kw + 262144;              // 262,144
  float* pM = vw + 262144;              // 65,536
  float* pL = pM + 65536;               // 65,536
  float* att = pL + 65536;              // 1,048,576
  float* woP = att + 1048576;           // 4 x 1,048,576

  const dim3 blk(256);
  // Fused QKV projection, split-K=4: grid 96x4x4 = 1536 blocks (~6/CU)
  gemm_nt_sk<<<dim3(96, 4, 4), blk, 0, stream>>>(
      x, Wq, Wk, Wv, 4096, 5120, qkvp, (size_t)256 * 6144, 4096, 1024, 6144);
  // RoPE + split-K reduce + scatter
  rope_scatter<<<dim3(3072), blk, 0, stream>>>(qkvp, qw, kw, vw);
  // Attention
  attn_partial<<<dim3(Bb * NKV * SSPLIT), blk, 0, stream>>>(
      qw, kw, vw, cacheK, cacheV, startp, pO, pM, pL);
  attn_combine<<<dim3(Bb * NQ * Tt), dim3(128), 0, stream>>>(pO, pM, pL, att);
  // Output projection, split-K=4: grid 64x4x4 = 1024 blocks (~4/CU)
  gemm_nt_sk<<<dim3(64, 4, 4), blk, 0, stream>>>(
      att, Wo, Wo, Wo, 4096, 4096, woP, (size_t)256 * 4096, 4096, 1024, 4096);
  reduce4<<<dim3(1024), blk, 0, stream>>>(woP, out);
}

// Round 5
// 653.536 us; speedup vs baseline: 1.0221x; 1.0221x over previous
//
#include <hip/hip_runtime.h>
#include <stdint.h>

#define Bb 8
#define Tt 32
#define Ee 4096
#define NQ 32
#define NKV 8
#define HD 128
#define CACHE_S 8192
#define SSPLIT 16
#define SCALE_F 0.08838834764831845f  // 1/sqrt(128)

typedef _Float16 half8 __attribute__((ext_vector_type(8)));
typedef _Float16 half4 __attribute__((ext_vector_type(4)));
typedef float f32x4 __attribute__((ext_vector_type(4)));

static __device__ __forceinline__ _Float16 f2h(float f) { return (_Float16)f; }

// ---------------------------------------------------------------------------
// Split-K GEMM: Cpart[z] = A[M x Kc] * W[N x Kc]^T for K-chunk z. fp32 in/out,
// f16 MFMA. 128x128 tiles (2x2 waves, 4x4 16x16 acc each), 32-wide K-slabs:
// 16 MFMA per wave per slab vs 8 float4 staging loads (2:1 density).
// Weight selected among {W0,W1,W2} by n0 (fused QKV; boundaries %128 == 0).
// ---------------------------------------------------------------------------
__global__ __launch_bounds__(256) void gemm_nt_sk(
    const float* __restrict__ A, const float* __restrict__ W0,
    const float* __restrict__ W1, const float* __restrict__ W2,
    int nsplit1, int nsplit2, float* __restrict__ Cpart, size_t part_stride,
    int K, int Kc, int ldc) {
  __shared__ _Float16 As[128][40];  // 32 k-cols + 8 pad
  __shared__ _Float16 Ws[128][40];
  const int n0 = blockIdx.x * 128;
  const int m0 = blockIdx.y * 128;
  const int kp = blockIdx.z;
  const int kbase = kp * Kc;
  const float* Wp;
  int nr0;
  if (n0 < nsplit1) { Wp = W0; nr0 = n0; }
  else if (n0 < nsplit2) { Wp = W1; nr0 = n0 - nsplit1; }
  else { Wp = W2; nr0 = n0 - nsplit2; }
  const int tid = threadIdx.x;
  const int lane = tid & 63;
  const int wave = tid >> 6;
  const int wm = (wave >> 1) * 64;
  const int wn = (wave & 1) * 64;
  const int l15 = lane & 15;
  const int quad = lane >> 4;
  const int sr = tid >> 3;        // staging row 0..31 (+p*32)
  const int sc = (tid & 7) * 4;   // staging col (floats) 0..28

  f32x4 acc[4][4];
#pragma unroll
  for (int i = 0; i < 4; i++)
#pragma unroll
    for (int j = 0; j < 4; j++) acc[i][j] = f32x4{0.f, 0.f, 0.f, 0.f};

  float4 pa[4], pw[4];
#pragma unroll
  for (int p = 0; p < 4; p++) {
    const int r = sr + p * 32;
    pa[p] = *(const float4*)&A[(size_t)(m0 + r) * K + kbase + sc];
    pw[p] = *(const float4*)&Wp[(size_t)(nr0 + r) * K + kbase + sc];
  }

  for (int k0 = 0; k0 < Kc; k0 += 32) {
    __syncthreads();
#pragma unroll
    for (int p = 0; p < 4; p++) {
      const int r = sr + p * 32;
      half4 ha = {f2h(pa[p].x), f2h(pa[p].y), f2h(pa[p].z), f2h(pa[p].w)};
      *(half4*)&As[r][sc] = ha;
      half4 hw = {f2h(pw[p].x), f2h(pw[p].y), f2h(pw[p].z), f2h(pw[p].w)};
      *(half4*)&Ws[r][sc] = hw;
    }
    __syncthreads();
    if (k0 + 32 < Kc) {  // prefetch next slab (overlaps MFMA below)
#pragma unroll
      for (int p = 0; p < 4; p++) {
        const int r = sr + p * 32;
        pa[p] = *(const float4*)&A[(size_t)(m0 + r) * K + kbase + k0 + 32 + sc];
        pw[p] = *(const float4*)&Wp[(size_t)(nr0 + r) * K + kbase + k0 + 32 + sc];
      }
    }
    const int kc = quad * 8;
    half8 af[4], wf[4];
#pragma unroll
    for (int i = 0; i < 4; i++) {
      af[i] = *(const half8*)&As[wm + i * 16 + l15][kc];
      wf[i] = *(const half8*)&Ws[wn + i * 16 + l15][kc];
    }
#pragma unroll
    for (int i = 0; i < 4; i++)
#pragma unroll
      for (int j = 0; j < 4; j++)
        acc[i][j] = __builtin_amdgcn_mfma_f32_16x16x32_f16(af[i], wf[j],
                                                           acc[i][j], 0, 0, 0);
  }
  float* Cp = Cpart + (size_t)kp * part_stride;
#pragma unroll
  for (int i = 0; i < 4; i++) {
    const int mr = m0 + wm + i * 16 + quad * 4;
#pragma unroll
    for (int j = 0; j < 4; j++) {
      const int nc = n0 + wn + j * 16 + l15;
#pragma unroll
      for (int r = 0; r < 4; r++)
        Cp[(size_t)(mr + r) * ldc + nc] = acc[i][j][r];
    }
  }
}

// ---------------------------------------------------------------------------
// Sum 8 split-K partials of qkv + RoPE (bugged: angle from HEAD index) +
// scatter to qw (B,NQ,T,HD), kw/vw (B,NKV,T,HD).
// ---------------------------------------------------------------------------
__global__ __launch_bounds__(256) void rope_scatter(
    const float* __restrict__ qkvp, float* __restrict__ qw,
    float* __restrict__ kw, float* __restrict__ vw) {
  const int pid = blockIdx.x * 256 + threadIdx.x;
  const int m = pid / 3072;
  const int c = pid - m * 3072;
  const int n = c * 2;
  const int b = m >> 5;
  const int t = m & 31;
  const size_t base = (size_t)m * 6144 + n;
  float a0 = 0.f, a1 = 0.f;
#pragma unroll
  for (int p = 0; p < 8; p++) {
    const float2 v = *(const float2*)&qkvp[p * 1572864 + base];
    a0 += v.x;
    a1 += v.y;
  }
  if (n < 4096) {  // q
    const int h = n >> 7;
    const int j = (n & 127) >> 1;
    const float invf = powf(10000.0f, -(float)j * (1.0f / 64.0f));
    float sn, cs;
    sincosf((float)h * invf, &sn, &cs);
    float* dst = qw + ((size_t)(b * NQ + h) * Tt + t) * HD + (j << 1);
    dst[0] = a0 * cs - a1 * sn;
    dst[1] = a0 * sn + a1 * cs;
  } else if (n < 5120) {  // k
    const int nn = n - 4096;
    const int h = nn >> 7;
    const int j = (nn & 127) >> 1;
    const float invf = powf(10000.0f, -(float)j * (1.0f / 64.0f));
    float sn, cs;
    sincosf((float)h * invf, &sn, &cs);
    float* dst = kw + ((size_t)(b * NKV + h) * Tt + t) * HD + (j << 1);
    dst[0] = a0 * cs - a1 * sn;
    dst[1] = a0 * sn + a1 * cs;
  } else {  // v
    const int nn = n - 5120;
    const int h = nn >> 7;
    const int d = nn & 127;
    float* dst = vw + ((size_t)(b * NKV + h) * Tt + t) * HD + d;
    dst[0] = a0;
    dst[1] = a1;
  }
}

// ---------------------------------------------------------------------------
// Flash-decode attention partials. Block = (b, kv-head g, split). 4 waves =
// 4 GQA q-heads. 32-key chunks staged in LDS; single register prefetch
// (R3 structure — two-deep regressed). SSPLIT=16 -> 1024 blocks (4/CU).
// pO stored f16 to keep partial traffic flat.
// ---------------------------------------------------------------------------
__global__ __launch_bounds__(256) void attn_partial(
    const float* __restrict__ qw, const float* __restrict__ kw,
    const float* __restrict__ vw, const float* __restrict__ cacheK,
    const float* __restrict__ cacheV, const int* __restrict__ startp,
    _Float16* __restrict__ pO, float* __restrict__ pM, float* __restrict__ pL) {
  const int blk = blockIdx.x;
  const int split = blk & (SSPLIT - 1);
  const int g = (blk / SSPLIT) & (NKV - 1);
  const int b = blk / (SSPLIT * NKV);
  const int start = *startp;
  const int end = start + Tt;
  int cl = ((end + SSPLIT * 32 - 1) / (SSPLIT * 32)) * 32;
  const int s_begin = split * cl;
  int s_end = s_begin + cl;
  if (s_end > end) s_end = end;

  const int tid = threadIdx.x;
  const int lane = tid & 63;
  const int wave = tid >> 6;
  const int l15 = lane & 15;
  const int quad = lane >> 4;
  const int h = g * 4 + wave;

  __shared__ _Float16 Ks[32][136];
  __shared__ _Float16 Vt[128][40];   // transposed V: d x keys
  __shared__ _Float16 Ps[4][32][40];

  const int str = tid >> 3;        // key row 0..31
  const int stc = (tid & 7) * 4;   // col base (floats), +u*32

  float4 pk[4], pv[4];
  auto load_chunk = [&](int s0) {
    const int sg = s0 + str;
    const bool valid = sg < end;
    const float* krow;
    const float* vrow;
    if (sg < start) {
      const size_t off = (((size_t)b * CACHE_S + sg) * NKV + g) * HD;
      krow = cacheK + off;
      vrow = cacheV + off;
    } else {
      int loc = sg - start;
      if (loc > Tt - 1) loc = Tt - 1;
      const size_t off = ((size_t)(b * NKV + g) * Tt + loc) * HD;
      krow = kw + off;
      vrow = vw + off;
    }
#pragma unroll
    for (int u = 0; u < 4; u++) {
      const int cc = stc + u * 32;
      pk[u] = valid ? *(const float4*)&krow[cc] : make_float4(0.f, 0.f, 0.f, 0.f);
      pv[u] = valid ? *(const float4*)&vrow[cc] : make_float4(0.f, 0.f, 0.f, 0.f);
    }
  };

  load_chunk(s_begin);  // issue longest-latency stream first

  // Q fragments (A-operand)
  half8 qf[2][4];
#pragma unroll
  for (int mt = 0; mt < 2; mt++) {
    const int t = mt * 16 + l15;
    const float* qrow = qw + ((size_t)(b * NQ + h) * Tt + t) * HD;
#pragma unroll
    for (int ks = 0; ks < 4; ks++) {
      const int d0 = ks * 32 + quad * 8;
      float4 v0 = *(const float4*)&qrow[d0];
      float4 v1 = *(const float4*)&qrow[d0 + 4];
      half8 hq = {f2h(v0.x), f2h(v0.y), f2h(v0.z), f2h(v0.w),
                  f2h(v1.x), f2h(v1.y), f2h(v1.z), f2h(v1.w)};
      qf[mt][ks] = hq;
    }
  }

  f32x4 Oacc[2][8];
#pragma unroll
  for (int mt = 0; mt < 2; mt++)
#pragma unroll
    for (int dt = 0; dt < 8; dt++) Oacc[mt][dt] = f32x4{0.f, 0.f, 0.f, 0.f};
  float mrow[2][4], lrow[2][4];
#pragma unroll
  for (int mt = 0; mt < 2; mt++)
#pragma unroll
    for (int rr = 0; rr < 4; rr++) { mrow[mt][rr] = -1e30f; lrow[mt][rr] = 0.f; }

  for (int s0 = s_begin; s0 < s_end; s0 += 32) {
    __syncthreads();
#pragma unroll
    for (int u = 0; u < 4; u++) {
      const int cc = stc + u * 32;
      half4 hk = {f2h(pk[u].x), f2h(pk[u].y), f2h(pk[u].z), f2h(pk[u].w)};
      *(half4*)&Ks[str][cc] = hk;
      Vt[cc + 0][str] = f2h(pv[u].x);
      Vt[cc + 1][str] = f2h(pv[u].y);
      Vt[cc + 2][str] = f2h(pv[u].z);
      Vt[cc + 3][str] = f2h(pv[u].w);
    }
    __syncthreads();
    if (s0 + 32 < s_end) load_chunk(s0 + 32);  // overlaps compute below

    // ---- scores ----
    f32x4 st[2][2];
#pragma unroll
    for (int mt = 0; mt < 2; mt++)
#pragma unroll
      for (int nt = 0; nt < 2; nt++) st[mt][nt] = f32x4{0.f, 0.f, 0.f, 0.f};
#pragma unroll
    for (int nt = 0; nt < 2; nt++) {
#pragma unroll
      for (int ks = 0; ks < 4; ks++) {
        half8 kf = *(const half8*)&Ks[nt * 16 + l15][ks * 32 + quad * 8];
        st[0][nt] = __builtin_amdgcn_mfma_f32_16x16x32_f16(qf[0][ks], kf, st[0][nt], 0, 0, 0);
        st[1][nt] = __builtin_amdgcn_mfma_f32_16x16x32_f16(qf[1][ks], kf, st[1][nt], 0, 0, 0);
      }
    }
#pragma unroll
    for (int mt = 0; mt < 2; mt++)
#pragma unroll
      for (int nt = 0; nt < 2; nt++)
#pragma unroll
        for (int rr = 0; rr < 4; rr++) {
          const int t = mt * 16 + quad * 4 + rr;
          const int sg = s0 + nt * 16 + l15;
          const float sv = st[mt][nt][rr] * SCALE_F;
          const bool masked = (sg > start + t) || (sg >= end);
          st[mt][nt][rr] = masked ? -1e30f : sv;
        }
    // ---- online softmax ----
#pragma unroll
    for (int mt = 0; mt < 2; mt++) {
      float rmax[4], rsum[4], al[4];
#pragma unroll
      for (int rr = 0; rr < 4; rr++)
        rmax[rr] = fmaxf(st[mt][0][rr], st[mt][1][rr]);
      for (int mm = 1; mm < 16; mm <<= 1)
#pragma unroll
        for (int rr = 0; rr < 4; rr++)
          rmax[rr] = fmaxf(rmax[rr], __shfl_xor(rmax[rr], mm));
#pragma unroll
      for (int rr = 0; rr < 4; rr++) {
        const float mn = fmaxf(mrow[mt][rr], rmax[rr]);
        al[rr] = __expf(mrow[mt][rr] - mn);
        mrow[mt][rr] = mn;
      }
#pragma unroll
      for (int nt = 0; nt < 2; nt++)
#pragma unroll
        for (int rr = 0; rr < 4; rr++)
          st[mt][nt][rr] = __expf(st[mt][nt][rr] - mrow[mt][rr]);
#pragma unroll
      for (int rr = 0; rr < 4; rr++) rsum[rr] = st[mt][0][rr] + st[mt][1][rr];
      for (int mm = 1; mm < 16; mm <<= 1)
#pragma unroll
        for (int rr = 0; rr < 4; rr++) rsum[rr] += __shfl_xor(rsum[rr], mm);
#pragma unroll
      for (int rr = 0; rr < 4; rr++)
        lrow[mt][rr] = lrow[mt][rr] * al[rr] + rsum[rr];
#pragma unroll
      for (int nt = 0; nt < 2; nt++)
#pragma unroll
        for (int rr = 0; rr < 4; rr++)
          Ps[wave][mt * 16 + quad * 4 + rr][nt * 16 + l15] = f2h(st[mt][nt][rr]);
#pragma unroll
      for (int dt = 0; dt < 8; dt++)
#pragma unroll
        for (int rr = 0; rr < 4; rr++) Oacc[mt][dt][rr] *= al[rr];
    }
    // ---- PV ----
    half8 pf0 = *(const half8*)&Ps[wave][l15][quad * 8];
    half8 pf1 = *(const half8*)&Ps[wave][16 + l15][quad * 8];
#pragma unroll
    for (int dt = 0; dt < 8; dt++) {
      half8 vf = *(const half8*)&Vt[dt * 16 + l15][quad * 8];
      Oacc[0][dt] = __builtin_amdgcn_mfma_f32_16x16x32_f16(pf0, vf, Oacc[0][dt], 0, 0, 0);
      Oacc[1][dt] = __builtin_amdgcn_mfma_f32_16x16x32_f16(pf1, vf, Oacc[1][dt], 0, 0, 0);
    }
  }

  const size_t rowbase = (size_t)(b * NQ + h) * Tt;
#pragma unroll
  for (int mt = 0; mt < 2; mt++)
#pragma unroll
    for (int rr = 0; rr < 4; rr++) {
      const int t = mt * 16 + quad * 4 + rr;
      const size_t pbase = ((rowbase + t) * SSPLIT + split) * (size_t)HD;
#pragma unroll
      for (int dt = 0; dt < 8; dt++)
        pO[pbase + dt * 16 + l15] = f2h(Oacc[mt][dt][rr]);
      if (l15 == 0) {
        pM[(rowbase + t) * SSPLIT + split] = mrow[mt][rr];
        pL[(rowbase + t) * SSPLIT + split] = lrow[mt][rr];
      }
    }
}

// ---------------------------------------------------------------------------
__global__ __launch_bounds__(128) void attn_combine(
    const _Float16* __restrict__ pO, const float* __restrict__ pM,
    const float* __restrict__ pL, float* __restrict__ att) {
  const int row = blockIdx.x;  // (b*NQ + h)*T + t
  const int d = threadIdx.x;
  float ms = -3.0e30f;
  float m[SSPLIT], l[SSPLIT];
#pragma unroll
  for (int i = 0; i < SSPLIT; i++) {
    m[i] = pM[row * SSPLIT + i];
    l[i] = pL[row * SSPLIT + i];
    ms = fmaxf(ms, m[i]);
  }
  float ls = 0.f, o = 0.f;
#pragma unroll
  for (int i = 0; i < SSPLIT; i++) {
    const float w = __expf(m[i] - ms);
    ls += l[i] * w;
    o += (float)pO[((size_t)row * SSPLIT + i) * HD + d] * w;
  }
  o /= fmaxf(ls, 1e-30f);
  const int b = row / (NQ * Tt);
  const int hh = (row / Tt) % NQ;
  const int t = row % Tt;
  att[((size_t)(b * Tt + t)) * Ee + hh * HD + d] = o;
}

// ---------------------------------------------------------------------------
// out = sum of 8 split-K partials (Wo), float4-vectorized.
// ---------------------------------------------------------------------------
__global__ __launch_bounds__(256) void reduce8(const float* __restrict__ p,
                                               float* __restrict__ out) {
  const int i = (blockIdx.x * 256 + threadIdx.x) * 4;
  float4 r = *(const float4*)&p[i];
#pragma unroll
  for (int z = 1; z < 8; z++) {
    float4 a = *(const float4*)&p[i + (size_t)z * 1048576];
    r.x += a.x; r.y += a.y; r.z += a.z; r.w += a.w;
  }
  *(float4*)&out[i] = r;
}

// ---------------------------------------------------------------------------
extern "C" void kernel_launch(void* const* d_in, const int* in_sizes, int n_in,
                              void* d_out, int out_size, void* d_ws,
                              size_t ws_size, hipStream_t stream) {
  const float* x = (const float*)d_in[0];
  const int* startp = (const int*)d_in[1];
  const float* cacheK = (const float*)d_in[2];
  const float* cacheV = (const float*)d_in[3];
  const float* Wq = (const float*)d_in[4];
  const float* Wk = (const float*)d_in[5];
  const float* Wv = (const float*)d_in[6];
  const float* Wo = (const float*)d_in[7];
  float* out = (float*)d_out;
  float* ws = (float*)d_ws;

  // workspace layout (float offsets)
  float* qkvp = ws;                          // 8 x 1,572,864 = 12,582,912
  _Float16* pO = (_Float16*)(ws + 12582912); // 16,777,216 halfs (8,388,608 fl)
  float* qw = ws + 20971520;                 // 1,048,576
  float* kw = qw + 1048576;                  // 262,144
  float* vw = kw + 262144;                   // 262,144
  float* pM = vw + 262144;                   // 131,072
  float* pL = pM + 131072;                   // 131,072
  float* att = pL + 131072;                  // 1,048,576
  float* woP = att + 1048576;                // 8 x 1,048,576

  const dim3 blk(256);
  // Fused QKV projection, 128x128 tiles, split-K=8: grid 48x2x8 = 768 blocks
  gemm_nt_sk<<<dim3(48, 2, 8), blk, 0, stream>>>(
      x, Wq, Wk, Wv, 4096, 5120, qkvp, (size_t)256 * 6144, 4096, 512, 6144);
  // RoPE + split-K reduce + scatter
  rope_scatter<<<dim3(3072), blk, 0, stream>>>(qkvp, qw, kw, vw);
  // Attention: 1024 blocks (4/CU)
  attn_partial<<<dim3(Bb * NKV * SSPLIT), blk, 0, stream>>>(
      qw, kw, vw, cacheK, cacheV, startp, pO, pM, pL);
  attn_combine<<<dim3(Bb * NQ * Tt), dim3(128), 0, stream>>>(pO, pM, pL, att);
  // Output projection, 128x128 tiles, split-K=8: grid 32x2x8 = 512 blocks
  gemm_nt_sk<<<dim3(32, 2, 8), blk, 0, stream>>>(
      att, Wo, Wo, Wo, 4096, 4096, woP, (size_t)256 * 4096, 4096, 512, 4096);
  reduce8<<<dim3(1024), blk, 0, stream>>>(woP, out);
}

// Round 6
// 642.508 us; speedup vs baseline: 1.0397x; 1.0172x over previous
//
#include <hip/hip_runtime.h>
#include <stdint.h>

#define Bb 8
#define Tt 32
#define Ee 4096
#define NQ 32
#define NKV 8
#define HD 128
#define CACHE_S 8192
#define SSPLIT 16
#define SCALE_F 0.08838834764831845f  // 1/sqrt(128)

typedef _Float16 half8 __attribute__((ext_vector_type(8)));
typedef _Float16 half4 __attribute__((ext_vector_type(4)));
typedef _Float16 half2v __attribute__((ext_vector_type(2)));
typedef float f32x4 __attribute__((ext_vector_type(4)));

static __device__ __forceinline__ _Float16 f2h(float f) { return (_Float16)f; }

// ---------------------------------------------------------------------------
// Split-K GEMM: Cpart[z] = A[M x Kc] * W[N x Kc]^T for K-chunk z. fp32 in,
// f16 MFMA, **f16 partial out** (halves split-K round-trip traffic; partial
// magnitudes ~0.5 so f16 rel err 5e-4 is well inside the 5.2e-3 budget).
// 128x128 tiles (2x2 waves, 4x4 16x16 acc each), 32-wide K-slabs.
// Weight selected among {W0,W1,W2} by n0 (fused QKV; boundaries %128 == 0).
// ---------------------------------------------------------------------------
__global__ __launch_bounds__(256) void gemm_nt_sk(
    const float* __restrict__ A, const float* __restrict__ W0,
    const float* __restrict__ W1, const float* __restrict__ W2,
    int nsplit1, int nsplit2, _Float16* __restrict__ Cpart,
    size_t part_stride, int K, int Kc, int ldc) {
  __shared__ _Float16 As[128][40];  // 32 k-cols + 8 pad
  __shared__ _Float16 Ws[128][40];
  const int n0 = blockIdx.x * 128;
  const int m0 = blockIdx.y * 128;
  const int kp = blockIdx.z;
  const int kbase = kp * Kc;
  const float* Wp;
  int nr0;
  if (n0 < nsplit1) { Wp = W0; nr0 = n0; }
  else if (n0 < nsplit2) { Wp = W1; nr0 = n0 - nsplit1; }
  else { Wp = W2; nr0 = n0 - nsplit2; }
  const int tid = threadIdx.x;
  const int lane = tid & 63;
  const int wave = tid >> 6;
  const int wm = (wave >> 1) * 64;
  const int wn = (wave & 1) * 64;
  const int l15 = lane & 15;
  const int quad = lane >> 4;
  const int sr = tid >> 3;        // staging row 0..31 (+p*32)
  const int sc = (tid & 7) * 4;   // staging col (floats) 0..28

  f32x4 acc[4][4];
#pragma unroll
  for (int i = 0; i < 4; i++)
#pragma unroll
    for (int j = 0; j < 4; j++) acc[i][j] = f32x4{0.f, 0.f, 0.f, 0.f};

  float4 pa[4], pw[4];
#pragma unroll
  for (int p = 0; p < 4; p++) {
    const int r = sr + p * 32;
    pa[p] = *(const float4*)&A[(size_t)(m0 + r) * K + kbase + sc];
    pw[p] = *(const float4*)&Wp[(size_t)(nr0 + r) * K + kbase + sc];
  }

  for (int k0 = 0; k0 < Kc; k0 += 32) {
    __syncthreads();
#pragma unroll
    for (int p = 0; p < 4; p++) {
      const int r = sr + p * 32;
      half4 ha = {f2h(pa[p].x), f2h(pa[p].y), f2h(pa[p].z), f2h(pa[p].w)};
      *(half4*)&As[r][sc] = ha;
      half4 hw = {f2h(pw[p].x), f2h(pw[p].y), f2h(pw[p].z), f2h(pw[p].w)};
      *(half4*)&Ws[r][sc] = hw;
    }
    __syncthreads();
    if (k0 + 32 < Kc) {  // prefetch next slab (overlaps MFMA below)
#pragma unroll
      for (int p = 0; p < 4; p++) {
        const int r = sr + p * 32;
        pa[p] = *(const float4*)&A[(size_t)(m0 + r) * K + kbase + k0 + 32 + sc];
        pw[p] = *(const float4*)&Wp[(size_t)(nr0 + r) * K + kbase + k0 + 32 + sc];
      }
    }
    const int kc = quad * 8;
    half8 af[4], wf[4];
#pragma unroll
    for (int i = 0; i < 4; i++) {
      af[i] = *(const half8*)&As[wm + i * 16 + l15][kc];
      wf[i] = *(const half8*)&Ws[wn + i * 16 + l15][kc];
    }
#pragma unroll
    for (int i = 0; i < 4; i++)
#pragma unroll
      for (int j = 0; j < 4; j++)
        acc[i][j] = __builtin_amdgcn_mfma_f32_16x16x32_f16(af[i], wf[j],
                                                           acc[i][j], 0, 0, 0);
  }
  _Float16* Cp = Cpart + (size_t)kp * part_stride;
#pragma unroll
  for (int i = 0; i < 4; i++) {
    const int mr = m0 + wm + i * 16 + quad * 4;
#pragma unroll
    for (int j = 0; j < 4; j++) {
      const int nc = n0 + wn + j * 16 + l15;
#pragma unroll
      for (int r = 0; r < 4; r++)
        Cp[(size_t)(mr + r) * ldc + nc] = f2h(acc[i][j][r]);
    }
  }
}

// ---------------------------------------------------------------------------
// Sum 8 f16 split-K partials of qkv + RoPE (bugged: angle from HEAD index) +
// scatter to qw (B,NQ,T,HD), kw/vw (B,NKV,T,HD).
// ---------------------------------------------------------------------------
__global__ __launch_bounds__(256) void rope_scatter(
    const _Float16* __restrict__ qkvp, float* __restrict__ qw,
    float* __restrict__ kw, float* __restrict__ vw) {
  const int pid = blockIdx.x * 256 + threadIdx.x;
  const int m = pid / 3072;
  const int c = pid - m * 3072;
  const int n = c * 2;
  const int b = m >> 5;
  const int t = m & 31;
  const size_t base = (size_t)m * 6144 + n;
  float a0 = 0.f, a1 = 0.f;
#pragma unroll
  for (int p = 0; p < 8; p++) {
    const half2v v = *(const half2v*)&qkvp[(size_t)p * 1572864 + base];
    a0 += (float)v[0];
    a1 += (float)v[1];
  }
  if (n < 4096) {  // q
    const int h = n >> 7;
    const int j = (n & 127) >> 1;
    const float invf = powf(10000.0f, -(float)j * (1.0f / 64.0f));
    float sn, cs;
    sincosf((float)h * invf, &sn, &cs);
    float* dst = qw + ((size_t)(b * NQ + h) * Tt + t) * HD + (j << 1);
    dst[0] = a0 * cs - a1 * sn;
    dst[1] = a0 * sn + a1 * cs;
  } else if (n < 5120) {  // k
    const int nn = n - 4096;
    const int h = nn >> 7;
    const int j = (nn & 127) >> 1;
    const float invf = powf(10000.0f, -(float)j * (1.0f / 64.0f));
    float sn, cs;
    sincosf((float)h * invf, &sn, &cs);
    float* dst = kw + ((size_t)(b * NKV + h) * Tt + t) * HD + (j << 1);
    dst[0] = a0 * cs - a1 * sn;
    dst[1] = a0 * sn + a1 * cs;
  } else {  // v
    const int nn = n - 5120;
    const int h = nn >> 7;
    const int d = nn & 127;
    float* dst = vw + ((size_t)(b * NKV + h) * Tt + t) * HD + d;
    dst[0] = a0;
    dst[1] = a1;
  }
}

// ---------------------------------------------------------------------------
// Flash-decode attention partials. Block = (b, kv-head g, split). 4 waves =
// 4 GQA q-heads. 32-key chunks staged in LDS; single register prefetch
// (two-deep regressed in R4). SSPLIT=16 -> 1024 blocks (4/CU). pO f16.
// ---------------------------------------------------------------------------
__global__ __launch_bounds__(256) void attn_partial(
    const float* __restrict__ qw, const float* __restrict__ kw,
    const float* __restrict__ vw, const float* __restrict__ cacheK,
    const float* __restrict__ cacheV, const int* __restrict__ startp,
    _Float16* __restrict__ pO, float* __restrict__ pM, float* __restrict__ pL) {
  const int blk = blockIdx.x;
  const int split = blk & (SSPLIT - 1);
  const int g = (blk / SSPLIT) & (NKV - 1);
  const int b = blk / (SSPLIT * NKV);
  const int start = *startp;
  const int end = start + Tt;
  int cl = ((end + SSPLIT * 32 - 1) / (SSPLIT * 32)) * 32;
  const int s_begin = split * cl;
  int s_end = s_begin + cl;
  if (s_end > end) s_end = end;

  const int tid = threadIdx.x;
  const int lane = tid & 63;
  const int wave = tid >> 6;
  const int l15 = lane & 15;
  const int quad = lane >> 4;
  const int h = g * 4 + wave;

  __shared__ _Float16 Ks[32][136];
  __shared__ _Float16 Vt[128][40];   // transposed V: d x keys
  __shared__ _Float16 Ps[4][32][40];

  const int str = tid >> 3;        // key row 0..31
  const int stc = (tid & 7) * 4;   // col base (floats), +u*32

  float4 pk[4], pv[4];
  auto load_chunk = [&](int s0) {
    const int sg = s0 + str;
    const bool valid = sg < end;
    const float* krow;
    const float* vrow;
    if (sg < start) {
      const size_t off = (((size_t)b * CACHE_S + sg) * NKV + g) * HD;
      krow = cacheK + off;
      vrow = cacheV + off;
    } else {
      int loc = sg - start;
      if (loc > Tt - 1) loc = Tt - 1;
      const size_t off = ((size_t)(b * NKV + g) * Tt + loc) * HD;
      krow = kw + off;
      vrow = vw + off;
    }
#pragma unroll
    for (int u = 0; u < 4; u++) {
      const int cc = stc + u * 32;
      pk[u] = valid ? *(const float4*)&krow[cc] : make_float4(0.f, 0.f, 0.f, 0.f);
      pv[u] = valid ? *(const float4*)&vrow[cc] : make_float4(0.f, 0.f, 0.f, 0.f);
    }
  };

  load_chunk(s_begin);  // issue longest-latency stream first

  // Q fragments (A-operand)
  half8 qf[2][4];
#pragma unroll
  for (int mt = 0; mt < 2; mt++) {
    const int t = mt * 16 + l15;
    const float* qrow = qw + ((size_t)(b * NQ + h) * Tt + t) * HD;
#pragma unroll
    for (int ks = 0; ks < 4; ks++) {
      const int d0 = ks * 32 + quad * 8;
      float4 v0 = *(const float4*)&qrow[d0];
      float4 v1 = *(const float4*)&qrow[d0 + 4];
      half8 hq = {f2h(v0.x), f2h(v0.y), f2h(v0.z), f2h(v0.w),
                  f2h(v1.x), f2h(v1.y), f2h(v1.z), f2h(v1.w)};
      qf[mt][ks] = hq;
    }
  }

  f32x4 Oacc[2][8];
#pragma unroll
  for (int mt = 0; mt < 2; mt++)
#pragma unroll
    for (int dt = 0; dt < 8; dt++) Oacc[mt][dt] = f32x4{0.f, 0.f, 0.f, 0.f};
  float mrow[2][4], lrow[2][4];
#pragma unroll
  for (int mt = 0; mt < 2; mt++)
#pragma unroll
    for (int rr = 0; rr < 4; rr++) { mrow[mt][rr] = -1e30f; lrow[mt][rr] = 0.f; }

  for (int s0 = s_begin; s0 < s_end; s0 += 32) {
    __syncthreads();
#pragma unroll
    for (int u = 0; u < 4; u++) {
      const int cc = stc + u * 32;
      half4 hk = {f2h(pk[u].x), f2h(pk[u].y), f2h(pk[u].z), f2h(pk[u].w)};
      *(half4*)&Ks[str][cc] = hk;
      Vt[cc + 0][str] = f2h(pv[u].x);
      Vt[cc + 1][str] = f2h(pv[u].y);
      Vt[cc + 2][str] = f2h(pv[u].z);
      Vt[cc + 3][str] = f2h(pv[u].w);
    }
    __syncthreads();
    if (s0 + 32 < s_end) load_chunk(s0 + 32);  // overlaps compute below

    // ---- scores ----
    f32x4 st[2][2];
#pragma unroll
    for (int mt = 0; mt < 2; mt++)
#pragma unroll
      for (int nt = 0; nt < 2; nt++) st[mt][nt] = f32x4{0.f, 0.f, 0.f, 0.f};
#pragma unroll
    for (int nt = 0; nt < 2; nt++) {
#pragma unroll
      for (int ks = 0; ks < 4; ks++) {
        half8 kf = *(const half8*)&Ks[nt * 16 + l15][ks * 32 + quad * 8];
        st[0][nt] = __builtin_amdgcn_mfma_f32_16x16x32_f16(qf[0][ks], kf, st[0][nt], 0, 0, 0);
        st[1][nt] = __builtin_amdgcn_mfma_f32_16x16x32_f16(qf[1][ks], kf, st[1][nt], 0, 0, 0);
      }
    }
#pragma unroll
    for (int mt = 0; mt < 2; mt++)
#pragma unroll
      for (int nt = 0; nt < 2; nt++)
#pragma unroll
        for (int rr = 0; rr < 4; rr++) {
          const int t = mt * 16 + quad * 4 + rr;
          const int sg = s0 + nt * 16 + l15;
          const float sv = st[mt][nt][rr] * SCALE_F;
          const bool masked = (sg > start + t) || (sg >= end);
          st[mt][nt][rr] = masked ? -1e30f : sv;
        }
    // ---- online softmax ----
#pragma unroll
    for (int mt = 0; mt < 2; mt++) {
      float rmax[4], rsum[4], al[4];
#pragma unroll
      for (int rr = 0; rr < 4; rr++)
        rmax[rr] = fmaxf(st[mt][0][rr], st[mt][1][rr]);
      for (int mm = 1; mm < 16; mm <<= 1)
#pragma unroll
        for (int rr = 0; rr < 4; rr++)
          rmax[rr] = fmaxf(rmax[rr], __shfl_xor(rmax[rr], mm));
#pragma unroll
      for (int rr = 0; rr < 4; rr++) {
        const float mn = fmaxf(mrow[mt][rr], rmax[rr]);
        al[rr] = __expf(mrow[mt][rr] - mn);
        mrow[mt][rr] = mn;
      }
#pragma unroll
      for (int nt = 0; nt < 2; nt++)
#pragma unroll
        for (int rr = 0; rr < 4; rr++)
          st[mt][nt][rr] = __expf(st[mt][nt][rr] - mrow[mt][rr]);
#pragma unroll
      for (int rr = 0; rr < 4; rr++) rsum[rr] = st[mt][0][rr] + st[mt][1][rr];
      for (int mm = 1; mm < 16; mm <<= 1)
#pragma unroll
        for (int rr = 0; rr < 4; rr++) rsum[rr] += __shfl_xor(rsum[rr], mm);
#pragma unroll
      for (int rr = 0; rr < 4; rr++)
        lrow[mt][rr] = lrow[mt][rr] * al[rr] + rsum[rr];
#pragma unroll
      for (int nt = 0; nt < 2; nt++)
#pragma unroll
        for (int rr = 0; rr < 4; rr++)
          Ps[wave][mt * 16 + quad * 4 + rr][nt * 16 + l15] = f2h(st[mt][nt][rr]);
#pragma unroll
      for (int dt = 0; dt < 8; dt++)
#pragma unroll
        for (int rr = 0; rr < 4; rr++) Oacc[mt][dt][rr] *= al[rr];
    }
    // ---- PV ----
    half8 pf0 = *(const half8*)&Ps[wave][l15][quad * 8];
    half8 pf1 = *(const half8*)&Ps[wave][16 + l15][quad * 8];
#pragma unroll
    for (int dt = 0; dt < 8; dt++) {
      half8 vf = *(const half8*)&Vt[dt * 16 + l15][quad * 8];
      Oacc[0][dt] = __builtin_amdgcn_mfma_f32_16x16x32_f16(pf0, vf, Oacc[0][dt], 0, 0, 0);
      Oacc[1][dt] = __builtin_amdgcn_mfma_f32_16x16x32_f16(pf1, vf, Oacc[1][dt], 0, 0, 0);
    }
  }

  const size_t rowbase = (size_t)(b * NQ + h) * Tt;
#pragma unroll
  for (int mt = 0; mt < 2; mt++)
#pragma unroll
    for (int rr = 0; rr < 4; rr++) {
      const int t = mt * 16 + quad * 4 + rr;
      const size_t pbase = ((rowbase + t) * SSPLIT + split) * (size_t)HD;
#pragma unroll
      for (int dt = 0; dt < 8; dt++)
        pO[pbase + dt * 16 + l15] = f2h(Oacc[mt][dt][rr]);
      if (l15 == 0) {
        pM[(rowbase + t) * SSPLIT + split] = mrow[mt][rr];
        pL[(rowbase + t) * SSPLIT + split] = lrow[mt][rr];
      }
    }
}

// ---------------------------------------------------------------------------
__global__ __launch_bounds__(128) void attn_combine(
    const _Float16* __restrict__ pO, const float* __restrict__ pM,
    const float* __restrict__ pL, float* __restrict__ att) {
  const int row = blockIdx.x;  // (b*NQ + h)*T + t
  const int d = threadIdx.x;
  float ms = -3.0e30f;
  float m[SSPLIT], l[SSPLIT];
#pragma unroll
  for (int i = 0; i < SSPLIT; i++) {
    m[i] = pM[row * SSPLIT + i];
    l[i] = pL[row * SSPLIT + i];
    ms = fmaxf(ms, m[i]);
  }
  float ls = 0.f, o = 0.f;
#pragma unroll
  for (int i = 0; i < SSPLIT; i++) {
    const float w = __expf(m[i] - ms);
    ls += l[i] * w;
    o += (float)pO[((size_t)row * SSPLIT + i) * HD + d] * w;
  }
  o /= fmaxf(ls, 1e-30f);
  const int b = row / (NQ * Tt);
  const int hh = (row / Tt) % NQ;
  const int t = row % Tt;
  att[((size_t)(b * Tt + t)) * Ee + hh * HD + d] = o;
}

// ---------------------------------------------------------------------------
// out = sum of 8 f16 split-K partials (Wo), accumulated in f32.
// ---------------------------------------------------------------------------
__global__ __launch_bounds__(256) void reduce8(const _Float16* __restrict__ p,
                                               float* __restrict__ out) {
  const int i = (blockIdx.x * 256 + threadIdx.x) * 4;
  float4 r = make_float4(0.f, 0.f, 0.f, 0.f);
#pragma unroll
  for (int z = 0; z < 8; z++) {
    half4 a = *(const half4*)&p[i + (size_t)z * 1048576];
    r.x += (float)a[0]; r.y += (float)a[1];
    r.z += (float)a[2]; r.w += (float)a[3];
  }
  *(float4*)&out[i] = r;
}

// ---------------------------------------------------------------------------
extern "C" void kernel_launch(void* const* d_in, const int* in_sizes, int n_in,
                              void* d_out, int out_size, void* d_ws,
                              size_t ws_size, hipStream_t stream) {
  const float* x = (const float*)d_in[0];
  const int* startp = (const int*)d_in[1];
  const float* cacheK = (const float*)d_in[2];
  const float* cacheV = (const float*)d_in[3];
  const float* Wq = (const float*)d_in[4];
  const float* Wk = (const float*)d_in[5];
  const float* Wv = (const float*)d_in[6];
  const float* Wo = (const float*)d_in[7];
  float* out = (float*)d_out;
  float* ws = (float*)d_ws;

  // workspace layout (float offsets)
  _Float16* qkvp = (_Float16*)ws;            // 8 x 1,572,864 halves = 6,291,456 fl
  _Float16* pO = (_Float16*)(ws + 6291456);  // 16,777,216 halves = 8,388,608 fl
  float* qw = ws + 14680064;                 // 1,048,576
  float* kw = qw + 1048576;                  // 262,144
  float* vw = kw + 262144;                   // 262,144
  float* pM = vw + 262144;                   // 131,072
  float* pL = pM + 131072;                   // 131,072
  float* att = pL + 131072;                  // 1,048,576
  _Float16* woP = (_Float16*)(att + 1048576);// 8 x 1,048,576 halves

  const dim3 blk(256);
  // Fused QKV projection, 128x128 tiles, split-K=8: grid 48x2x8 = 768 blocks
  gemm_nt_sk<<<dim3(48, 2, 8), blk, 0, stream>>>(
      x, Wq, Wk, Wv, 4096, 5120, qkvp, (size_t)256 * 6144, 4096, 512, 6144);
  // RoPE + split-K reduce + scatter
  rope_scatter<<<dim3(3072), blk, 0, stream>>>(qkvp, qw, kw, vw);
  // Attention: 1024 blocks (4/CU)
  attn_partial<<<dim3(Bb * NKV * SSPLIT), blk, 0, stream>>>(
      qw, kw, vw, cacheK, cacheV, startp, pO, pM, pL);
  attn_combine<<<dim3(Bb * NQ * Tt), dim3(128), 0, stream>>>(pO, pM, pL, att);
  // Output projection, 128x128 tiles, split-K=8: grid 32x2x8 = 512 blocks
  gemm_nt_sk<<<dim3(32, 2, 8), blk, 0, stream>>>(
      att, Wo, Wo, Wo, 4096, 4096, woP, (size_t)256 * 4096, 4096, 512, 4096);
  reduce8<<<dim3(1024), blk, 0, stream>>>(woP, out);
}